// Round 5
// baseline (2332.477 us; speedup 1.0000x reference)
//
#include <hip/hip_runtime.h>
#include <math.h>

#define LRELU(v) ((v) > 0.f ? (v) : 0.01f * (v))

typedef __attribute__((ext_vector_type(8))) short bf8v;   // 8 x bf16 (4 VGPRs)
typedef __attribute__((ext_vector_type(4))) float f4v;    // MFMA accumulator

// fp32 -> bf16 round-to-nearest-even
static __device__ __forceinline__ unsigned short f2b(float f) {
    unsigned int u = __float_as_uint(f);
    unsigned int r = (u + 0x7fffu + ((u >> 16) & 1u)) >> 16;
    return (unsigned short)r;
}

// async global->LDS, 16B per lane; LDS dest must be linear (base + tid*16).
static __device__ __forceinline__ void gload16(const unsigned short* g, unsigned short* l) {
    __builtin_amdgcn_global_load_lds(
        (__attribute__((address_space(1))) void*)(g),
        (__attribute__((address_space(3))) void*)(l), 16, 0, 0);
}

// ---------------------------------------------------------------------------
// K1: build zero-ring-padded full-res image, pixel-major bf16 [194*194][16]
// ---------------------------------------------------------------------------
__global__ __launch_bounds__(256) void k_build_full(const float* __restrict__ in,
                                                    unsigned short* __restrict__ full0p) {
    int idx = blockIdx.x * 256 + threadIdx.x;
    if (idx >= 368640) return;
    int c = idx % 10, pix = idx / 10;
    int X = pix % 192, Y = pix / 192;
    int t = (Y & 3) * 4 + (X & 3);
    int h = Y >> 2, w = X >> 2;
    int pp = (Y + 1) * 194 + (X + 1);
    full0p[(size_t)pp * 16 + c] = f2b(in[(((t * 10 + c) * 48) + h) * 48 + w]);
}

// ---------------------------------------------------------------------------
// K2: weight convert+permute fp32 -> bf16.
// ---------------------------------------------------------------------------
template <int C, int CP, int Q>
__global__ __launch_bounds__(256) void k_wcvt(const float* __restrict__ src,
                                              unsigned short* __restrict__ dst,
                                              int Mv, int Kp) {
    int m = blockIdx.x;
    for (int kp = threadIdx.x; kp < Kp; kp += 256) {
        int qq = kp / CP, c = kp - qq * CP;
        float v = 0.f;
        if (m < Mv && c < C && qq < Q)
            v = src[((size_t)m * C + c) * Q + qq];
        dst[(size_t)m * Kp + kp] = f2b(v);
    }
}

// K2b: flat fp32 -> bf16 convert
__global__ __launch_bounds__(256) void k_cvt_flat(const float* __restrict__ src,
                                                  unsigned short* __restrict__ dst,
                                                  size_t n) {
    size_t i = ((size_t)blockIdx.x * 256 + threadIdx.x) * 4;
    if (i >= n) return;
    float4 v = *(const float4*)(src + i);
    ushort4 o;
    o.x = f2b(v.x); o.y = f2b(v.y); o.z = f2b(v.z); o.w = f2b(v.w);
    *(ushort4*)(dst + i) = o;
}

// ---------------------------------------------------------------------------
// K4: im2col 4x4 stride4 from PADDED feature map [194*194][104]
// ---------------------------------------------------------------------------
__global__ __launch_bounds__(256) void k_im2col4(const unsigned short* __restrict__ src,
                                                 unsigned short* __restrict__ dst) {
    int p = blockIdx.x;  // 0..2303
    int x = p % 48, y = p / 48;
    for (int kp = threadIdx.x; kp < 1600; kp += 256) {
        int qq = kp / 100, c = kp - qq * 100;
        int yy = y * 4 + (qq >> 2), xx = x * 4 + (qq & 3);
        dst[(size_t)p * 1600 + kp] = src[(size_t)((yy + 1) * 194 + (xx + 1)) * 104 + c];
    }
}

// ---------------------------------------------------------------------------
// K5: MFMA GEMM (m97 2-phase structure) — head gemm + fallbacks.
// ---------------------------------------------------------------------------
template <int ACT, int OF32, int REMAP, int SWZ>
__global__ __launch_bounds__(256) void k_gemm(
    const unsigned short* __restrict__ A, const unsigned short* __restrict__ Bt,
    const float* __restrict__ bias, void* __restrict__ outv,
    int K, int Mv, int ldout) {
    __shared__ __align__(16) unsigned short As[128 * 32];
    __shared__ __align__(16) unsigned short Bs[128 * 32];
    const int tid = threadIdx.x;
    const int lane = tid & 63;
    const int w = tid >> 6;
    const int wm = w >> 1, wn = w & 1;
    const int q = lane >> 4, ln = lane & 15;
    int bx = blockIdx.x, by = blockIdx.y;
    if (SWZ) {
        int gx = gridDim.x;
        int nwg = gx * gridDim.y;
        int lin = by * gx + bx;
        int qq = nwg >> 3, rr = nwg & 7;
        int xcd = lin & 7, idx = lin >> 3;
        int wg = (xcd < rr ? xcd * (qq + 1) : rr * (qq + 1) + (xcd - rr) * qq) + idx;
        bx = wg % gx; by = wg / gx;
    }
    const int m0 = by * 128, n0 = bx * 128;

    f4v acc[4][4];
#pragma unroll
    for (int i = 0; i < 4; ++i)
#pragma unroll
        for (int j = 0; j < 4; ++j) acc[i][j] = (f4v){0.f, 0.f, 0.f, 0.f};

    const int br0 = tid >> 2, bk0 = (tid & 3) << 3;
    const unsigned short* pA0 = A + (size_t)(m0 + br0) * K + bk0;
    const unsigned short* pA1 = pA0 + (size_t)64 * K;
    const unsigned short* pB0 = Bt + (size_t)(n0 + br0) * K + bk0;
    const unsigned short* pB1 = pB0 + (size_t)64 * K;
    unsigned short* lA0 = As + tid * 8;
    unsigned short* lA1 = As + 2048 + tid * 8;
    unsigned short* lB0 = Bs + tid * 8;
    unsigned short* lB1 = Bs + 2048 + tid * 8;
    const unsigned short* Ap2 = &As[(wm * 64 + ln) * 32 + q * 8];
    const unsigned short* Bp2 = &Bs[(wn * 64 + ln) * 32 + q * 8];

    for (int k0 = 0; k0 < K; k0 += 32) {
        gload16(pA0 + k0, lA0);
        gload16(pA1 + k0, lA1);
        gload16(pB0 + k0, lB0);
        gload16(pB1 + k0, lB1);
        __syncthreads();
        bf8v af[4], bfv[4];
#pragma unroll
        for (int i = 0; i < 4; ++i) af[i] = *(const bf8v*)(Ap2 + i * 512);
#pragma unroll
        for (int j = 0; j < 4; ++j) bfv[j] = *(const bf8v*)(Bp2 + j * 512);
#pragma unroll
        for (int i = 0; i < 4; ++i)
#pragma unroll
            for (int j = 0; j < 4; ++j)
                acc[i][j] = __builtin_amdgcn_mfma_f32_16x16x32_bf16(af[i], bfv[j], acc[i][j], 0, 0, 0);
        __syncthreads();
    }

    float* tb = ((float*)As) + w * 288;
#pragma unroll
    for (int i = 0; i < 4; ++i) {
        const int mbase = m0 + wm * 64 + i * 16;
        float bi[4];
#pragma unroll
        for (int r = 0; r < 4; ++r) {
            int mm = mbase + q * 4 + r;
            bi[r] = (mm < Mv) ? bias[mm] : 0.f;
        }
#pragma unroll
        for (int j = 0; j < 4; ++j) {
            const int nbase = n0 + wn * 64 + j * 16;
#pragma unroll
            for (int r = 0; r < 4; ++r) {
                float v = acc[i][j][r] + bi[r];
                v = ACT ? tanhf(v) : LRELU(v);
                tb[ln * 17 + q * 4 + r] = v;
            }
#pragma unroll
            for (int r = 0; r < 4; ++r) {
                float v = tb[(q * 4 + r) * 17 + ln];
                int n = nbase + q * 4 + r;
                int m = mbase + ln;
                if (m < Mv) {
                    if (REMAP == 3) {
                        int y = n / 48, x = n - y * 48;
                        size_t np = (size_t)((y + 1) * 50 + x + 1);
                        ((unsigned short*)outv)[np * (size_t)ldout + m] = f2b(v);
                    } else {
                        if (OF32) ((float*)outv)[(size_t)n * ldout + m] = v;
                        else ((unsigned short*)outv)[(size_t)n * ldout + m] = f2b(v);
                    }
                }
            }
        }
    }
}

// ---------------------------------------------------------------------------
// K5big v3: 256x256 deep-pipelined GEMM, 4 phases/K-tile with read-ahead.
// Sync skeleton IDENTICAL to the verified round-3 kernel (lgkm0 -> bar ->
// stage(cur,t+2) -> vmcnt(8) -> bar per tile).  Within a tile, the 64 MFMAs
// split into 4 phases of 16 (ks x mf-half); each phase's ds-reads issue one
// phase AHEAD (the LDS pipe serves them while the matrix pipe runs the
// previous cluster), and the NEXT tile's first-phase reads issue from the
// other dbuf right after vmcnt(8) confirms it, overlapping the last cluster.
// sched_group_barrier pins the DS_READ/MFMA interleave (r4 showed plain
// source order is not preserved).  Accumulation order per element is
// ks0-then-ks1, tiles ascending — bit-identical to rounds 2-4.
// ---------------------------------------------------------------------------
template <int ACT, int OF32, int SWZ>
__global__ __launch_bounds__(512, 1) void k_gemm256(
    const unsigned short* __restrict__ A, const unsigned short* __restrict__ Bt,
    const float* __restrict__ bias, void* __restrict__ outv,
    int K, int Mv, int ldout) {
    __shared__ __align__(16) unsigned short As[2][16384];
    __shared__ __align__(16) unsigned short Bs[2][16384];
    const int tid = threadIdx.x;          // 0..511
    const int lane = tid & 63;
    const int w = tid >> 6;               // 0..7
    const int wm = w >> 2;                // 0..1
    const int wn = w & 3;                 // 0..3
    const int q = lane >> 4, ln = lane & 15;

    int bx = blockIdx.x, by = blockIdx.y;
    if (SWZ) {
        int gx = gridDim.x;
        int nwg = gx * gridDim.y;
        int qq = nwg >> 3, rr = nwg & 7;
        int lin = by * gx + bx;
        int xcd = lin & 7, idx = lin >> 3;
        int wg = (xcd < rr ? xcd * (qq + 1) : rr * (qq + 1) + (xcd - rr) * qq) + idx;
        bx = wg % gx; by = wg / gx;
    }
    const int m0 = by * 256, n0 = bx * 256;

    f4v acc[8][4];
#pragma unroll
    for (int i = 0; i < 8; ++i)
#pragma unroll
        for (int j = 0; j < 4; ++j) acc[i][j] = (f4v){0.f, 0.f, 0.f, 0.f};

    // staging: chunk c = r*512+tid -> row r*64 + (tid>>3), 16B-chunk tid&7
    const int srow = tid >> 3;            // 0..63
    const int sj = tid & 7;
    const int sjx = sj ^ (srow & 7);      // pre-swizzled source chunk (involution)
    const unsigned short* gA = A + (size_t)(m0 + srow) * K + sjx * 8;
    const unsigned short* gB = Bt + (size_t)(n0 + srow) * K + sjx * 8;
    const size_t rstride = (size_t)64 * K;
    unsigned short* lA = &As[0][0] + tid * 8;
    unsigned short* lB = &Bs[0][0] + tid * 8;

#define STAGE256(buf, t)                                               \
    {                                                                  \
        const unsigned short* ga_ = gA + (size_t)(t) * 64;             \
        const unsigned short* gb_ = gB + (size_t)(t) * 64;             \
        unsigned short* la_ = lA + (buf) * 16384;                      \
        unsigned short* lb_ = lB + (buf) * 16384;                      \
        _Pragma("unroll")                                              \
        for (int r_ = 0; r_ < 4; ++r_) {                               \
            gload16(ga_ + r_ * rstride, la_ + r_ * 4096);              \
            gload16(gb_ + r_ * rstride, lb_ + r_ * 4096);              \
        }                                                              \
    }

    // read offsets (elts).  row&7 == ln&7 for all fragment rows.
    int aoff[8], boff[4];
#pragma unroll
    for (int mf = 0; mf < 8; ++mf) aoff[mf] = (wm * 128 + mf * 16 + ln) * 64;
#pragma unroll
    for (int nf = 0; nf < 4; ++nf) boff[nf] = (wn * 64 + nf * 16 + ln) * 64;
    const int l7 = ln & 7;
    const int koff0 = ((0 * 4 + q) ^ l7) * 8;   // ks=0
    const int koff1 = ((1 * 4 + q) ^ l7) * 8;   // ks=1

    const int NT = K >> 6;
    STAGE256(0, 0);
    STAGE256(1, 1);
    asm volatile("s_waitcnt vmcnt(8)" ::: "memory");
    __builtin_amdgcn_sched_barrier(0);
    __builtin_amdgcn_s_barrier();

    bf8v A0h0[4], A0h1[4], A1h0[4], A1h1[4], B0v[4], B1v[4];
    // prologue: P0 reads of tile 0
    {
        const unsigned short* as = &As[0][0];
        const unsigned short* bs = &Bs[0][0];
#pragma unroll
        for (int i = 0; i < 4; ++i) A0h0[i] = *(const bf8v*)&as[aoff[i] + koff0];
#pragma unroll
        for (int j = 0; j < 4; ++j) B0v[j] = *(const bf8v*)&bs[boff[j] + koff0];
    }

    for (int t = 0; t < NT; ++t) {
        const int cur = t & 1;
        const unsigned short* as = &As[cur][0];
        const unsigned short* bs = &Bs[cur][0];
        const unsigned short* asn = &As[cur ^ 1][0];
        const unsigned short* bsn = &Bs[cur ^ 1][0];

        // P1 reads (A ks0 half1)
#pragma unroll
        for (int i = 0; i < 4; ++i) A0h1[i] = *(const bf8v*)&as[aoff[4 + i] + koff0];
        __builtin_amdgcn_sched_group_barrier(0x100, 4, 0);   // 4 DS_READ
        // MFMA P0: acc[0..3] += A0h0 x B0 (ks0)
        __builtin_amdgcn_s_setprio(1);
#pragma unroll
        for (int i = 0; i < 4; ++i)
#pragma unroll
            for (int nf = 0; nf < 4; ++nf)
                acc[i][nf] = __builtin_amdgcn_mfma_f32_16x16x32_bf16(A0h0[i], B0v[nf], acc[i][nf], 0, 0, 0);
        __builtin_amdgcn_s_setprio(0);
        __builtin_amdgcn_sched_group_barrier(0x8, 16, 0);    // 16 MFMA

        // P2 reads (A ks1 half0 + B ks1)
#pragma unroll
        for (int i = 0; i < 4; ++i) A1h0[i] = *(const bf8v*)&as[aoff[i] + koff1];
#pragma unroll
        for (int j = 0; j < 4; ++j) B1v[j] = *(const bf8v*)&bs[boff[j] + koff1];
        __builtin_amdgcn_sched_group_barrier(0x100, 8, 0);
        // MFMA P1: acc[4..7] += A0h1 x B0 (ks0)
        __builtin_amdgcn_s_setprio(1);
#pragma unroll
        for (int i = 0; i < 4; ++i)
#pragma unroll
            for (int nf = 0; nf < 4; ++nf)
                acc[4 + i][nf] = __builtin_amdgcn_mfma_f32_16x16x32_bf16(A0h1[i], B0v[nf], acc[4 + i][nf], 0, 0, 0);
        __builtin_amdgcn_s_setprio(0);
        __builtin_amdgcn_sched_group_barrier(0x8, 16, 0);

        // P3 reads (A ks1 half1)
#pragma unroll
        for (int i = 0; i < 4; ++i) A1h1[i] = *(const bf8v*)&as[aoff[4 + i] + koff1];
        __builtin_amdgcn_sched_group_barrier(0x100, 4, 0);
        // MFMA P2: acc[0..3] += A1h0 x B1 (ks1)
        __builtin_amdgcn_s_setprio(1);
#pragma unroll
        for (int i = 0; i < 4; ++i)
#pragma unroll
            for (int nf = 0; nf < 4; ++nf)
                acc[i][nf] = __builtin_amdgcn_mfma_f32_16x16x32_bf16(A1h0[i], B1v[nf], acc[i][nf], 0, 0, 0);
        __builtin_amdgcn_s_setprio(0);
        __builtin_amdgcn_sched_group_barrier(0x8, 16, 0);

        // all reads of buf[cur] drained before staging overwrites it
        asm volatile("s_waitcnt lgkmcnt(0)" ::: "memory");
        __builtin_amdgcn_sched_barrier(0);
        __builtin_amdgcn_s_barrier();
        if (t + 2 < NT) {
            STAGE256(cur, t + 2);
            asm volatile("s_waitcnt vmcnt(8)" ::: "memory");  // tile t+1 landed
        } else {
            asm volatile("s_waitcnt vmcnt(0)" ::: "memory");
        }
        __builtin_amdgcn_sched_barrier(0);
        __builtin_amdgcn_s_barrier();

        // P0 reads of tile t+1 from the other dbuf (landed per vmcnt above)
        if (t + 1 < NT) {
#pragma unroll
            for (int i = 0; i < 4; ++i) A0h0[i] = *(const bf8v*)&asn[aoff[i] + koff0];
#pragma unroll
            for (int j = 0; j < 4; ++j) B0v[j] = *(const bf8v*)&bsn[boff[j] + koff0];
            __builtin_amdgcn_sched_group_barrier(0x100, 8, 0);
        }
        // MFMA P3: acc[4..7] += A1h1 x B1 (ks1) — regs drained by lgkm0 above
        __builtin_amdgcn_s_setprio(1);
#pragma unroll
        for (int i = 0; i < 4; ++i)
#pragma unroll
            for (int nf = 0; nf < 4; ++nf)
                acc[4 + i][nf] = __builtin_amdgcn_mfma_f32_16x16x32_bf16(A1h1[i], B1v[nf], acc[4 + i][nf], 0, 0, 0);
        __builtin_amdgcn_s_setprio(0);
        __builtin_amdgcn_sched_group_barrier(0x8, 16, 0);
    }
    __builtin_amdgcn_s_barrier();
#undef STAGE256

    // transposed epilogue, per-wave 16x17 tile (intra-wave only)
    float* tb = ((float*)&As[0][0]) + w * 288;
#pragma unroll
    for (int mf = 0; mf < 8; ++mf) {
        const int mbase = m0 + wm * 128 + mf * 16;
        float bi[4];
#pragma unroll
        for (int r = 0; r < 4; ++r) {
            int mm = mbase + q * 4 + r;
            bi[r] = (mm < Mv) ? bias[mm] : 0.f;
        }
#pragma unroll
        for (int nf = 0; nf < 4; ++nf) {
            const int nbase = n0 + wn * 64 + nf * 16;
#pragma unroll
            for (int r = 0; r < 4; ++r) {
                float v = acc[mf][nf][r] + bi[r];
                v = ACT ? tanhf(v) : LRELU(v);
                tb[ln * 17 + q * 4 + r] = v;
            }
#pragma unroll
            for (int r = 0; r < 4; ++r) {
                float v = tb[(q * 4 + r) * 17 + ln];
                int n = nbase + q * 4 + r;
                int m = mbase + ln;
                if (m < Mv) {
                    if (OF32) ((float*)outv)[(size_t)n * ldout + m] = v;
                    else ((unsigned short*)outv)[(size_t)n * ldout + m] = f2b(v);
                }
            }
        }
    }
}

// ---------------------------------------------------------------------------
// K5c: conv3x3-as-GEMM with implicit im2col (128-row M tile; verified).
// ---------------------------------------------------------------------------
template <int TAPK, int CST, int SH, int REMAP>
__global__ __launch_bounds__(256) void k_cgemm(
    const unsigned short* __restrict__ A, const unsigned short* __restrict__ Bt,
    const float* __restrict__ bias, unsigned short* __restrict__ outp,
    int Mv, int ldout) {
    __shared__ __align__(16) unsigned short As[128 * 32];
    __shared__ __align__(16) unsigned short Bs[128 * 32];
    const int tid = threadIdx.x;
    const int lane = tid & 63;
    const int w = tid >> 6;
    const int wm = w >> 1, wn = w & 1;
    const int q = lane >> 4, ln = lane & 15;
    const int m0 = blockIdx.y * 128, n0 = blockIdx.x * 128;
    const int KA = 9 * TAPK;

    f4v acc[4][4];
#pragma unroll
    for (int i = 0; i < 4; ++i)
#pragma unroll
        for (int j = 0; j < 4; ++j) acc[i][j] = (f4v){0.f, 0.f, 0.f, 0.f};

    const int br0 = tid >> 2, bk0 = (tid & 3) << 3;
    const unsigned short* pA0 = A + (size_t)(m0 + br0) * KA + bk0;
    const unsigned short* pA1 = pA0 + (size_t)64 * KA;
    unsigned short* lA0 = As + tid * 8;
    unsigned short* lA1 = As + 2048 + tid * 8;
    unsigned short* lB0 = Bs + tid * 8;
    unsigned short* lB1 = Bs + 2048 + tid * 8;
    const unsigned short* Ap2 = &As[(wm * 64 + ln) * 32 + q * 8];
    const unsigned short* Bp2 = &Bs[(wn * 64 + ln) * 32 + q * 8];

#pragma unroll
    for (int tap = 0; tap < 9; ++tap) {
        const int sh = (tap / 3 - 1) * SH + (tap % 3 - 1);
        const unsigned short* pB0 = Bt + (long)(n0 + br0 + sh) * CST + bk0;
        const unsigned short* pB1 = pB0 + (long)64 * CST;
        const int kab = tap * TAPK;
        for (int kk = 0; kk < TAPK; kk += 32) {
            gload16(pA0 + kab + kk, lA0);
            gload16(pA1 + kab + kk, lA1);
            gload16(pB0 + kk, lB0);
            gload16(pB1 + kk, lB1);
            __syncthreads();
            bf8v af[4], bfv[4];
#pragma unroll
            for (int i = 0; i < 4; ++i) af[i] = *(const bf8v*)(Ap2 + i * 512);
#pragma unroll
            for (int j = 0; j < 4; ++j) bfv[j] = *(const bf8v*)(Bp2 + j * 512);
#pragma unroll
            for (int i = 0; i < 4; ++i)
#pragma unroll
                for (int j = 0; j < 4; ++j)
                    acc[i][j] = __builtin_amdgcn_mfma_f32_16x16x32_bf16(af[i], bfv[j], acc[i][j], 0, 0, 0);
            __syncthreads();
        }
    }

    float* tb = ((float*)As) + w * 288;
#pragma unroll
    for (int i = 0; i < 4; ++i) {
        const int mbase = m0 + wm * 64 + i * 16;
        float bi[4];
#pragma unroll
        for (int r = 0; r < 4; ++r) {
            int mm = mbase + q * 4 + r;
            bi[r] = (mm < Mv) ? bias[mm] : 0.f;
        }
#pragma unroll
        for (int j = 0; j < 4; ++j) {
            const int nbase = n0 + wn * 64 + j * 16;
#pragma unroll
            for (int r = 0; r < 4; ++r) {
                float v = acc[i][j][r] + bi[r];
                v = LRELU(v);
                tb[ln * 17 + q * 4 + r] = v;
            }
#pragma unroll
            for (int r = 0; r < 4; ++r) {
                float v = tb[(q * 4 + r) * 17 + ln];
                int n = nbase + q * 4 + r;
                int m = mbase + ln;
                if (m < Mv) {
                    if (REMAP == 1) {
                        int y = n / 194, x = n - y * 194;
                        bool z = (n >= 37636) || y == 0 || y >= 193 || x == 0 || x >= 193;
                        outp[(size_t)n * ldout + m] = f2b(z ? 0.f : v);
                    } else if (REMAP == 2) {
                        int y = n / 50, x = n - y * 50;
                        bool z = (n >= 2500) || y == 0 || y >= 49 || x == 0 || x >= 49;
                        outp[(size_t)n * ldout + m] = f2b(z ? 0.f : v);
                    } else if (REMAP == 4) {
                        int y = n / 50, x = n - y * 50;
                        if (n < 2500 && y >= 1 && y <= 48 && x >= 1 && x <= 48)
                            outp[(size_t)((y - 1) * 48 + (x - 1)) * ldout + m] = f2b(v);
                    }
                }
            }
        }
    }
}

// ---------------------------------------------------------------------------
// K5c64: conv3x3 cgemm with 64-row M tile (4 waves as 1M x 4N, wave 64x32).
// ---------------------------------------------------------------------------
template <int TAPK, int CST, int SH, int REMAP>
__global__ __launch_bounds__(256) void k_cgemm64(
    const unsigned short* __restrict__ A, const unsigned short* __restrict__ Bt,
    const float* __restrict__ bias, unsigned short* __restrict__ outp,
    int Mv, int ldout) {
    __shared__ __align__(16) unsigned short As[64 * 32];
    __shared__ __align__(16) unsigned short Bs[128 * 32];
    const int tid = threadIdx.x;
    const int lane = tid & 63;
    const int wn = tid >> 6;  // 0..3
    const int q = lane >> 4, ln = lane & 15;
    const int m0 = blockIdx.y * 64, n0 = blockIdx.x * 128;
    const int KA = 9 * TAPK;

    f4v acc[4][2];
#pragma unroll
    for (int i = 0; i < 4; ++i)
#pragma unroll
        for (int j = 0; j < 2; ++j) acc[i][j] = (f4v){0.f, 0.f, 0.f, 0.f};

    const int br0 = tid >> 2, bk0 = (tid & 3) << 3;  // br0 0..63
    const unsigned short* pA0 = A + (size_t)(m0 + br0) * KA + bk0;
    unsigned short* lA0 = As + tid * 8;
    unsigned short* lB0 = Bs + tid * 8;
    unsigned short* lB1 = Bs + 2048 + tid * 8;
    const unsigned short* Ap2 = &As[ln * 32 + q * 8];
    const unsigned short* Bp2 = &Bs[(wn * 32 + ln) * 32 + q * 8];

#pragma unroll
    for (int tap = 0; tap < 9; ++tap) {
        const int sh = (tap / 3 - 1) * SH + (tap % 3 - 1);
        const unsigned short* pB0 = Bt + (long)(n0 + br0 + sh) * CST + bk0;
        const unsigned short* pB1 = pB0 + (long)64 * CST;
        const int kab = tap * TAPK;
        for (int kk = 0; kk < TAPK; kk += 32) {
            gload16(pA0 + kab + kk, lA0);
            gload16(pB0 + kk, lB0);
            gload16(pB1 + kk, lB1);
            __syncthreads();
            bf8v af[4], bfv[2];
#pragma unroll
            for (int i = 0; i < 4; ++i) af[i] = *(const bf8v*)(Ap2 + i * 512);
#pragma unroll
            for (int j = 0; j < 2; ++j) bfv[j] = *(const bf8v*)(Bp2 + j * 512);
#pragma unroll
            for (int i = 0; i < 4; ++i)
#pragma unroll
                for (int j = 0; j < 2; ++j)
                    acc[i][j] = __builtin_amdgcn_mfma_f32_16x16x32_bf16(af[i], bfv[j], acc[i][j], 0, 0, 0);
            __syncthreads();
        }
    }

    float* tb = ((float*)Bs) + wn * 288;
#pragma unroll
    for (int i = 0; i < 4; ++i) {
        const int mbase = m0 + i * 16;
        float bi[4];
#pragma unroll
        for (int r = 0; r < 4; ++r) {
            int mm = mbase + q * 4 + r;
            bi[r] = (mm < Mv) ? bias[mm] : 0.f;
        }
#pragma unroll
        for (int j = 0; j < 2; ++j) {
            const int nbase = n0 + wn * 32 + j * 16;
#pragma unroll
            for (int r = 0; r < 4; ++r) {
                float v = acc[i][j][r] + bi[r];
                v = LRELU(v);
                tb[ln * 17 + q * 4 + r] = v;
            }
#pragma unroll
            for (int r = 0; r < 4; ++r) {
                float v = tb[(q * 4 + r) * 17 + ln];
                int n = nbase + q * 4 + r;
                int m = mbase + ln;
                if (m < Mv) {
                    if (REMAP == 2) {
                        int y = n / 50, x = n - y * 50;
                        bool z = (n >= 2500) || y == 0 || y >= 49 || x == 0 || x >= 49;
                        outp[(size_t)n * ldout + m] = f2b(z ? 0.f : v);
                    } else if (REMAP == 4) {
                        int y = n / 50, x = n - y * 50;
                        if (n < 2500 && y >= 1 && y <= 48 && x >= 1 && x <= 48)
                            outp[(size_t)((y - 1) * 48 + (x - 1)) * ldout + m] = f2b(v);
                    }
                }
            }
        }
    }
}

// ---------------------------------------------------------------------------
// K5b: legacy reg-staged GEMM with in-loop fp32->bf16 A conversion (fallback)
// ---------------------------------------------------------------------------
template <int ACT, int OF32, int AF32>
__global__ __launch_bounds__(256) void k_gemm_f32a(
    const void* __restrict__ Ain, const unsigned short* __restrict__ Bt,
    const float* __restrict__ bias, void* __restrict__ outv,
    int K, int Mv, int ldout) {
    __shared__ __align__(16) unsigned short As[128 * 40];
    __shared__ __align__(16) unsigned short Bs[128 * 40];
    const int tid = threadIdx.x;
    const int lane = tid & 63;
    const int w = tid >> 6;
    const int wm = w >> 1, wn = w & 1;
    const int q = lane >> 4, ln = lane & 15;
    const int m0 = blockIdx.y * 128, n0 = blockIdx.x * 128;

    f4v acc[4][4];
#pragma unroll
    for (int i = 0; i < 4; ++i)
#pragma unroll
        for (int j = 0; j < 4; ++j) acc[i][j] = (f4v){0.f, 0.f, 0.f, 0.f};

    const int br0 = tid >> 2, bk0 = (tid & 3) << 3;
    const int br1 = br0 + 64;
    const int bl0 = br0 * 40 + bk0, bl1 = br1 * 40 + bk0;
    const unsigned short* pB0 = Bt + (size_t)(n0 + br0) * K + bk0;
    const unsigned short* pB1 = Bt + (size_t)(n0 + br1) * K + bk0;

    const unsigned short* Ab = (const unsigned short*)Ain;
    const float* Af = (const float*)Ain;
    const unsigned short* pA0 = Ab + (size_t)(m0 + br0) * K + bk0;
    const unsigned short* pA1 = Ab + (size_t)(m0 + br1) * K + bk0;
    const int fr = tid >> 3, fk = (tid & 7) << 2;
    const float* pF = Af + (size_t)(m0 + fr) * K + fk;

    for (int k0 = 0; k0 < K; k0 += 32) {
        if (AF32) {
#pragma unroll
            for (int jj = 0; jj < 4; ++jj) {
                float4 v = *(const float4*)(pF + (size_t)jj * 32 * K + k0);
                unsigned int lo = ((unsigned)f2b(v.y) << 16) | f2b(v.x);
                unsigned int hi = ((unsigned)f2b(v.w) << 16) | f2b(v.z);
                *(uint2*)&As[(fr + jj * 32) * 40 + fk] = make_uint2(lo, hi);
            }
        } else {
            uint4 a0 = *(const uint4*)(pA0 + k0);
            uint4 a1 = *(const uint4*)(pA1 + k0);
            *(uint4*)&As[bl0] = a0;
            *(uint4*)&As[bl1] = a1;
        }
        uint4 b0 = *(const uint4*)(pB0 + k0);
        uint4 b1 = *(const uint4*)(pB1 + k0);
        *(uint4*)&Bs[bl0] = b0;
        *(uint4*)&Bs[bl1] = b1;
        __syncthreads();
        const unsigned short* Ap2 = &As[(wm * 64 + ln) * 40 + q * 8];
        const unsigned short* Bp2 = &Bs[(wn * 64 + ln) * 40 + q * 8];
        bf8v af[4], bfv[4];
#pragma unroll
        for (int i = 0; i < 4; ++i) af[i] = *(const bf8v*)(Ap2 + i * 640);
#pragma unroll
        for (int j = 0; j < 4; ++j) bfv[j] = *(const bf8v*)(Bp2 + j * 640);
#pragma unroll
        for (int i = 0; i < 4; ++i)
#pragma unroll
            for (int j = 0; j < 4; ++j)
                acc[i][j] = __builtin_amdgcn_mfma_f32_16x16x32_bf16(af[i], bfv[j], acc[i][j], 0, 0, 0);
        __syncthreads();
    }

    float* tb = ((float*)As) + w * 288;
#pragma unroll
    for (int i = 0; i < 4; ++i) {
        const int mbase = m0 + wm * 64 + i * 16;
        float bi[4];
#pragma unroll
        for (int r = 0; r < 4; ++r) {
            int mm = mbase + q * 4 + r;
            bi[r] = (mm < Mv) ? bias[mm] : 0.f;
        }
#pragma unroll
        for (int j = 0; j < 4; ++j) {
            const int nbase = n0 + wn * 64 + j * 16;
#pragma unroll
            for (int r = 0; r < 4; ++r) {
                float v = acc[i][j][r] + bi[r];
                v = ACT ? tanhf(v) : LRELU(v);
                tb[ln * 17 + q * 4 + r] = v;
            }
#pragma unroll
            for (int r = 0; r < 4; ++r) {
                float v = tb[(q * 4 + r) * 17 + ln];
                size_t n = nbase + q * 4 + r;
                int m = mbase + ln;
                if (m < Mv) {
                    if (OF32) ((float*)outv)[n * (size_t)ldout + m] = v;
                    else ((unsigned short*)outv)[n * (size_t)ldout + m] = f2b(v);
                }
            }
        }
    }
}

// ---------------------------------------------------------------------------
// K6: per-pixel normal equations + solve (verified, unchanged)
// ---------------------------------------------------------------------------
__global__ __launch_bounds__(256) void k_solve(const float* __restrict__ WmT,
                                               const float* __restrict__ design,
                                               const float* __restrict__ input,
                                               float* __restrict__ out) {
    const int p = blockIdx.x;  // 0..2303
    const int h = p / 48, wpx = p % 48;
    const int tid = threadIdx.x;
    __shared__ float Msh[16 * 17];
    __shared__ float Gsh[16 * 17];
    __shared__ float Xsh[16 * 8];
    __shared__ float Ysh[16 * 4];
    __shared__ float XTWsh[7 * 17];
    __shared__ float Aacc[49];
    __shared__ float Bacc[21];
    __shared__ float parash[21];

    if (tid < 49) Aacc[tid] = 0.f;
    if (tid >= 64 && tid < 85) Bacc[tid - 64] = 0.f;
    __syncthreads();

    const float* wrow = WmT + (size_t)p * 12544;
    for (int ni = 0; ni < 49; ++ni) {
        {
            int t1 = tid >> 4, t2 = tid & 15;
            Msh[t1 * 17 + t2] = wrow[ni * 256 + tid];
        }
        int sy = h + ni / 7 - 3, sx = wpx + ni % 7 - 3;
        bool inb = (sy >= 0 && sy < 48 && sx >= 0 && sx < 48);
        if (tid < 112) {
            int t = tid / 7, c = tid - t * 7;
            Xsh[t * 8 + c] = inb ? design[(size_t)(t * 7 + c) * 2304 + sy * 48 + sx] : 0.f;
        } else if (tid >= 128 && tid < 176) {
            int l = tid - 128;
            int t = l / 3, r = l - t * 3;
            Ysh[t * 4 + r] = inb ? input[(size_t)(t * 10 + r) * 2304 + sy * 48 + sx] : 0.f;
        }
        __syncthreads();
        {
            int t1 = tid >> 4, t2 = tid & 15;
            float s = (t1 == t2) ? 1.f : 0.f;
#pragma unroll
            for (int k = 0; k < 16; ++k) s += Msh[t1 * 17 + k] * Msh[t2 * 17 + k];
            Gsh[t1 * 17 + t2] = s;
        }
        __syncthreads();
        if (tid < 112) {
            int c = tid >> 4, t2 = tid & 15;
            float s = 0.f;
#pragma unroll
            for (int t1 = 0; t1 < 16; ++t1) s += Xsh[t1 * 8 + c] * Gsh[t1 * 17 + t2];
            XTWsh[c * 17 + t2] = s;
        }
        __syncthreads();
        if (tid < 49) {
            int c1 = tid / 7, c2 = tid - c1 * 7;
            float s = 0.f;
#pragma unroll
            for (int t = 0; t < 16; ++t) s += XTWsh[c1 * 17 + t] * Xsh[t * 8 + c2];
            Aacc[tid] += s;
        } else if (tid >= 64 && tid < 85) {
            int l = tid - 64;
            int c = l / 3, r = l - c * 3;
            float s = 0.f;
#pragma unroll
            for (int t = 0; t < 16; ++t) s += XTWsh[c * 17 + t] * Ysh[t * 4 + r];
            Bacc[l] += s;
        }
        __syncthreads();
    }

    if (tid == 0) {
        float Mg[7][10];
#pragma unroll
        for (int i = 0; i < 7; ++i) {
#pragma unroll
            for (int j = 0; j < 7; ++j) Mg[i][j] = Aacc[i * 7 + j] + ((i == j) ? 0.01f : 0.f);
#pragma unroll
            for (int r = 0; r < 3; ++r) Mg[i][7 + r] = Bacc[i * 3 + r];
        }
#pragma unroll
        for (int kk = 0; kk < 7; ++kk) {
            float inv = 1.f / Mg[kk][kk];
#pragma unroll
            for (int j = 0; j < 10; ++j) Mg[kk][j] *= inv;
#pragma unroll
            for (int i = 0; i < 7; ++i) {
                if (i == kk) continue;
                float f = Mg[i][kk];
#pragma unroll
                for (int j = 0; j < 10; ++j) Mg[i][j] -= f * Mg[kk][j];
            }
        }
#pragma unroll
        for (int c = 0; c < 7; ++c)
#pragma unroll
            for (int r = 0; r < 3; ++r) parash[c * 3 + r] = Mg[c][7 + r];
    }
    __syncthreads();

    if (tid < 48) {
        int t = tid / 3, r = tid - t * 3;
        float s = 0.f;
#pragma unroll
        for (int c = 0; c < 7; ++c)
            s += design[(size_t)(t * 7 + c) * 2304 + p] * parash[c * 3 + r];
        out[(size_t)tid * 2304 + p] = s;
    }
}

// ---------------------------------------------------------------------------
extern "C" void kernel_launch(void* const* d_in, const int* in_sizes, int n_in,
                              void* d_out, int out_size, void* d_ws, size_t ws_size,
                              hipStream_t stream) {
    const float* input   = (const float*)d_in[0];
    const float* design  = (const float*)d_in[1];
    const float* fw0     = (const float*)d_in[2];
    const float* fb0     = (const float*)d_in[3];
    const float* fw_rest = (const float*)d_in[4];
    const float* fb_rest = (const float*)d_in[5];
    const float* ww0     = (const float*)d_in[6];
    const float* wb0     = (const float*)d_in[7];
    const float* ww_mid  = (const float*)d_in[8];
    const float* wb_mid  = (const float*)d_in[9];
    const float* ww1     = (const float*)d_in[10];
    const float* wb1     = (const float*)d_in[11];
    const float* ww2     = (const float*)d_in[12];
    const float* wb2     = (const float*)d_in[13];
    float* out = (float*)d_out;
    float* ws = (float*)d_ws;

    // ---- workspace layout (float units).  Region [0, 28,901,376) is scratch
    // during the conv phase and becomes WmT (fp32 [2304][12544]) at ww2 time.
    float* WmT = ws;
    unsigned short* full0p = (unsigned short*)(ws + 40000);      // [37956][16] sh
    unsigned short* actPA  = (unsigned short*)(ws + 350000);     // [37956][104] sh
    unsigned short* actPB  = (unsigned short*)(ws + 2330000);    // [37956][104] sh
    unsigned short* fw0c   = (unsigned short*)(ws + 4310000);    // [128][288] sh
    unsigned short* fwrb   = (unsigned short*)(ws + 4330000);    // 13 x [128][1152] sh
    unsigned short* ww0b   = (unsigned short*)(ws + 5290000);    // [1024][1600] sh
    unsigned short* col4   = (unsigned short*)(ws + 6110000);    // [2304][1600] sh
    unsigned short* gPA    = (unsigned short*)(ws + 7960000);    // [2688][1024] sh
    unsigned short* gPB    = (unsigned short*)(ws + 9340000);    // [2688][1024] sh
    unsigned short* wmb    = (unsigned short*)(ws + 10720000);   // [1024][9216] sh
    unsigned short* gcmp   = (unsigned short*)(ws + 15440000);   // [2304][1024] sh
    unsigned short* g1     = (unsigned short*)(ws + 28901376);   // [2304][6272] sh
    unsigned short* ww1b   = (unsigned short*)(ws + 36126720);   // fallback slot
    const size_t WS_BASE_F = 39337984ull;
    unsigned short* ww2b   = (unsigned short*)(ws + WS_BASE_F);  // [12544][6272] sh (19,668,992 f)
    unsigned short* ww1bp  = (unsigned short*)(ws + 59006976);   // [6400][1024] sh (3,276,800 f)
    const size_t NEED_BIG = 59006976ull + 3276800ull;            // 62,283,776 f

    // ---- zero padded buffers (ring + tails)
    hipMemsetAsync(full0p, 0, (size_t)37956 * 16 * 2, stream);
    hipMemsetAsync(actPA, 0, (size_t)37956 * 104 * 2, stream);
    hipMemsetAsync(actPB, 0, (size_t)37956 * 104 * 2, stream);
    hipMemsetAsync(gPA, 0, (size_t)2688 * 1024 * 2, stream);
    hipMemsetAsync(gPB, 0, (size_t)2688 * 1024 * 2, stream);

    const size_t haveF = ws_size / 4;
    const bool big = (haveF >= NEED_BIG) && (haveF >= WS_BASE_F + 39337984ull);

    // ---- weight conversions
    k_wcvt<10, 32, 9><<<128, 256, 0, stream>>>(fw0, fw0c, 100, 288);
    for (int i = 0; i < 13; ++i)
        k_wcvt<100, 128, 9><<<128, 256, 0, stream>>>(fw_rest + (size_t)i * 90000,
                                                     fwrb + (size_t)i * 147456, 100, 1152);
    k_wcvt<100, 100, 16><<<1024, 256, 0, stream>>>(ww0, ww0b, 1024, 1600);
    if (big)
        k_wcvt<1024, 1024, 1><<<6400, 256, 0, stream>>>(ww1, ww1bp, 6272, 1024);
    else
        k_wcvt<1024, 1024, 1><<<6272, 256, 0, stream>>>(ww1, ww1b, 6272, 1024);

    // ---- feature network: 14 conv3x3 via implicit-im2col cgemm (padded 194x194)
    k_build_full<<<1440, 256, 0, stream>>>(input, full0p);
    k_cgemm<32, 16, 194, 1><<<dim3(295, 1), 256, 0, stream>>>(fw0c, full0p, fb0, actPA, 100, 104);
    unsigned short* src = actPA;
    unsigned short* dst = actPB;
    for (int i = 0; i < 13; ++i) {
        k_cgemm<128, 104, 194, 1><<<dim3(295, 1), 256, 0, stream>>>(
            fwrb + (size_t)i * 147456, src, fb_rest + i * 100, dst, 100, 104);
        unsigned short* t = src; src = dst; dst = t;
    }
    // src == final feature map (padded)

    // ---- weight network head: conv4x4 s4 -> padded 50x50 [1024]
    k_im2col4<<<2304, 256, 0, stream>>>(src, col4);
    k_gemm<0, 0, 3, 0><<<dim3(18, 8), 256, 0, stream>>>(ww0b, col4, wb0, gPA, 1600, 1024, 1024);

    // ---- 3 x conv3x3 1024->1024 at 48x48 via 64-row-tile cgemm (320 blocks)
    k_wcvt<1024, 1024, 9><<<1024, 256, 0, stream>>>(ww_mid, wmb, 1024, 9216);
    k_cgemm64<1024, 1024, 50, 2><<<dim3(20, 16), 256, 0, stream>>>(wmb, gPA, wb_mid, gPB, 1024, 1024);
    k_wcvt<1024, 1024, 9><<<1024, 256, 0, stream>>>(ww_mid + (size_t)9437184, wmb, 1024, 9216);
    k_cgemm64<1024, 1024, 50, 2><<<dim3(20, 16), 256, 0, stream>>>(wmb, gPB, wb_mid + 1024, gPA, 1024, 1024);
    k_wcvt<1024, 1024, 9><<<1024, 256, 0, stream>>>(ww_mid + (size_t)2 * 9437184, wmb, 1024, 9216);
    k_cgemm64<1024, 1024, 50, 4><<<dim3(20, 16), 256, 0, stream>>>(wmb, gPA, wb_mid + 2048, gcmp, 1024, 1024);

    // ---- two 1x1 convs (GEMMs)
    if (big) {
        k_gemm256<0, 0, 1><<<dim3(9, 25), 512, 0, stream>>>(ww1bp, gcmp, wb1, g1, 1024, 6272, 6272);
        k_cvt_flat<<<76832, 256, 0, stream>>>(ww2, ww2b, (size_t)12544 * 6272);
        k_gemm256<1, 1, 1><<<dim3(9, 49), 512, 0, stream>>>(ww2b, g1, wb2, WmT, 6272, 12544, 12544);
    } else {
        k_gemm<0, 0, 0, 1><<<dim3(18, 49), 256, 0, stream>>>(ww1b, gcmp, wb1, g1, 1024, 6272, 6272);
        k_gemm_f32a<1, 1, 1><<<dim3(18, 98), 256, 0, stream>>>(ww2, g1, wb2, WmT, 6272, 12544, 12544);
    }

    // ---- per-pixel solve
    k_solve<<<2304, 256, 0, stream>>>(WmT, design, input, out);
}

// Round 6
// 2310.922 us; speedup vs baseline: 1.0093x; 1.0093x over previous
//
#include <hip/hip_runtime.h>
#include <math.h>

#define LRELU(v) ((v) > 0.f ? (v) : 0.01f * (v))

typedef __attribute__((ext_vector_type(8))) short bf8v;   // 8 x bf16 (4 VGPRs)
typedef __attribute__((ext_vector_type(4))) float f4v;    // MFMA accumulator

// fp32 -> bf16 round-to-nearest-even
static __device__ __forceinline__ unsigned short f2b(float f) {
    unsigned int u = __float_as_uint(f);
    unsigned int r = (u + 0x7fffu + ((u >> 16) & 1u)) >> 16;
    return (unsigned short)r;
}

// async global->LDS, 16B per lane; LDS dest must be linear (base + tid*16).
static __device__ __forceinline__ void gload16(const unsigned short* g, unsigned short* l) {
    __builtin_amdgcn_global_load_lds(
        (__attribute__((address_space(1))) void*)(g),
        (__attribute__((address_space(3))) void*)(l), 16, 0, 0);
}

// ---------------------------------------------------------------------------
// K1: build zero-ring-padded full-res image, pixel-major bf16 [194*194][16]
// ---------------------------------------------------------------------------
__global__ __launch_bounds__(256) void k_build_full(const float* __restrict__ in,
                                                    unsigned short* __restrict__ full0p) {
    int idx = blockIdx.x * 256 + threadIdx.x;
    if (idx >= 368640) return;
    int c = idx % 10, pix = idx / 10;
    int X = pix % 192, Y = pix / 192;
    int t = (Y & 3) * 4 + (X & 3);
    int h = Y >> 2, w = X >> 2;
    int pp = (Y + 1) * 194 + (X + 1);
    full0p[(size_t)pp * 16 + c] = f2b(in[(((t * 10 + c) * 48) + h) * 48 + w]);
}

// ---------------------------------------------------------------------------
// K2: weight convert+permute fp32 -> bf16.
// ---------------------------------------------------------------------------
template <int C, int CP, int Q>
__global__ __launch_bounds__(256) void k_wcvt(const float* __restrict__ src,
                                              unsigned short* __restrict__ dst,
                                              int Mv, int Kp) {
    int m = blockIdx.x;
    for (int kp = threadIdx.x; kp < Kp; kp += 256) {
        int qq = kp / CP, c = kp - qq * CP;
        float v = 0.f;
        if (m < Mv && c < C && qq < Q)
            v = src[((size_t)m * C + c) * Q + qq];
        dst[(size_t)m * Kp + kp] = f2b(v);
    }
}

// K2b: flat fp32 -> bf16 convert
__global__ __launch_bounds__(256) void k_cvt_flat(const float* __restrict__ src,
                                                  unsigned short* __restrict__ dst,
                                                  size_t n) {
    size_t i = ((size_t)blockIdx.x * 256 + threadIdx.x) * 4;
    if (i >= n) return;
    float4 v = *(const float4*)(src + i);
    ushort4 o;
    o.x = f2b(v.x); o.y = f2b(v.y); o.z = f2b(v.z); o.w = f2b(v.w);
    *(ushort4*)(dst + i) = o;
}

// ---------------------------------------------------------------------------
// K4: im2col 4x4 stride4 from PADDED feature map [194*194][104]
// ---------------------------------------------------------------------------
__global__ __launch_bounds__(256) void k_im2col4(const unsigned short* __restrict__ src,
                                                 unsigned short* __restrict__ dst) {
    int p = blockIdx.x;  // 0..2303
    int x = p % 48, y = p / 48;
    for (int kp = threadIdx.x; kp < 1600; kp += 256) {
        int qq = kp / 100, c = kp - qq * 100;
        int yy = y * 4 + (qq >> 2), xx = x * 4 + (qq & 3);
        dst[(size_t)p * 1600 + kp] = src[(size_t)((yy + 1) * 194 + (xx + 1)) * 104 + c];
    }
}

// ---------------------------------------------------------------------------
// K5: MFMA GEMM (m97 2-phase structure) — head gemm + fallbacks.
// ---------------------------------------------------------------------------
template <int ACT, int OF32, int REMAP, int SWZ>
__global__ __launch_bounds__(256) void k_gemm(
    const unsigned short* __restrict__ A, const unsigned short* __restrict__ Bt,
    const float* __restrict__ bias, void* __restrict__ outv,
    int K, int Mv, int ldout) {
    __shared__ __align__(16) unsigned short As[128 * 32];
    __shared__ __align__(16) unsigned short Bs[128 * 32];
    const int tid = threadIdx.x;
    const int lane = tid & 63;
    const int w = tid >> 6;
    const int wm = w >> 1, wn = w & 1;
    const int q = lane >> 4, ln = lane & 15;
    int bx = blockIdx.x, by = blockIdx.y;
    if (SWZ) {
        int gx = gridDim.x;
        int nwg = gx * gridDim.y;
        int lin = by * gx + bx;
        int qq = nwg >> 3, rr = nwg & 7;
        int xcd = lin & 7, idx = lin >> 3;
        int wg = (xcd < rr ? xcd * (qq + 1) : rr * (qq + 1) + (xcd - rr) * qq) + idx;
        bx = wg % gx; by = wg / gx;
    }
    const int m0 = by * 128, n0 = bx * 128;

    f4v acc[4][4];
#pragma unroll
    for (int i = 0; i < 4; ++i)
#pragma unroll
        for (int j = 0; j < 4; ++j) acc[i][j] = (f4v){0.f, 0.f, 0.f, 0.f};

    const int br0 = tid >> 2, bk0 = (tid & 3) << 3;
    const unsigned short* pA0 = A + (size_t)(m0 + br0) * K + bk0;
    const unsigned short* pA1 = pA0 + (size_t)64 * K;
    const unsigned short* pB0 = Bt + (size_t)(n0 + br0) * K + bk0;
    const unsigned short* pB1 = pB0 + (size_t)64 * K;
    unsigned short* lA0 = As + tid * 8;
    unsigned short* lA1 = As + 2048 + tid * 8;
    unsigned short* lB0 = Bs + tid * 8;
    unsigned short* lB1 = Bs + 2048 + tid * 8;
    const unsigned short* Ap2 = &As[(wm * 64 + ln) * 32 + q * 8];
    const unsigned short* Bp2 = &Bs[(wn * 64 + ln) * 32 + q * 8];

    for (int k0 = 0; k0 < K; k0 += 32) {
        gload16(pA0 + k0, lA0);
        gload16(pA1 + k0, lA1);
        gload16(pB0 + k0, lB0);
        gload16(pB1 + k0, lB1);
        __syncthreads();
        bf8v af[4], bfv[4];
#pragma unroll
        for (int i = 0; i < 4; ++i) af[i] = *(const bf8v*)(Ap2 + i * 512);
#pragma unroll
        for (int j = 0; j < 4; ++j) bfv[j] = *(const bf8v*)(Bp2 + j * 512);
#pragma unroll
        for (int i = 0; i < 4; ++i)
#pragma unroll
            for (int j = 0; j < 4; ++j)
                acc[i][j] = __builtin_amdgcn_mfma_f32_16x16x32_bf16(af[i], bfv[j], acc[i][j], 0, 0, 0);
        __syncthreads();
    }

    float* tb = ((float*)As) + w * 288;
#pragma unroll
    for (int i = 0; i < 4; ++i) {
        const int mbase = m0 + wm * 64 + i * 16;
        float bi[4];
#pragma unroll
        for (int r = 0; r < 4; ++r) {
            int mm = mbase + q * 4 + r;
            bi[r] = (mm < Mv) ? bias[mm] : 0.f;
        }
#pragma unroll
        for (int j = 0; j < 4; ++j) {
            const int nbase = n0 + wn * 64 + j * 16;
#pragma unroll
            for (int r = 0; r < 4; ++r) {
                float v = acc[i][j][r] + bi[r];
                v = ACT ? tanhf(v) : LRELU(v);
                tb[ln * 17 + q * 4 + r] = v;
            }
#pragma unroll
            for (int r = 0; r < 4; ++r) {
                float v = tb[(q * 4 + r) * 17 + ln];
                int n = nbase + q * 4 + r;
                int m = mbase + ln;
                if (m < Mv) {
                    if (REMAP == 3) {
                        int y = n / 48, x = n - y * 48;
                        size_t np = (size_t)((y + 1) * 50 + x + 1);
                        ((unsigned short*)outv)[np * (size_t)ldout + m] = f2b(v);
                    } else {
                        if (OF32) ((float*)outv)[(size_t)n * ldout + m] = v;
                        else ((unsigned short*)outv)[(size_t)n * ldout + m] = f2b(v);
                    }
                }
            }
        }
    }
}

// ---------------------------------------------------------------------------
// K5big (round-3 verified version, 459 us): 256x256 deep-pipelined GEMM.
// Per tile t: read all frags -> MFMA ks0 -> lgkm0; bar -> stage(cur,t+2);
// vmcnt(8) -> bar -> MFMA ks1.  r4/r5 intra-tile pipelining variants both
// regressed; this is the proven optimum for this structure.
// ---------------------------------------------------------------------------
template <int ACT, int OF32, int SWZ>
__global__ __launch_bounds__(512, 1) void k_gemm256(
    const unsigned short* __restrict__ A, const unsigned short* __restrict__ Bt,
    const float* __restrict__ bias, void* __restrict__ outv,
    int K, int Mv, int ldout) {
    __shared__ __align__(16) unsigned short As[2][16384];
    __shared__ __align__(16) unsigned short Bs[2][16384];
    const int tid = threadIdx.x;          // 0..511
    const int lane = tid & 63;
    const int w = tid >> 6;               // 0..7
    const int wm = w >> 2;                // 0..1
    const int wn = w & 3;                 // 0..3
    const int q = lane >> 4, ln = lane & 15;

    int bx = blockIdx.x, by = blockIdx.y;
    if (SWZ) {
        int gx = gridDim.x;
        int nwg = gx * gridDim.y;
        int lin = by * gx + bx;
        int qq = nwg >> 3, rr = nwg & 7;
        int xcd = lin & 7, idx = lin >> 3;
        int wg = (xcd < rr ? xcd * (qq + 1) : rr * (qq + 1) + (xcd - rr) * qq) + idx;
        bx = wg % gx; by = wg / gx;
    }
    const int m0 = by * 256, n0 = bx * 256;

    f4v acc[8][4];
#pragma unroll
    for (int i = 0; i < 8; ++i)
#pragma unroll
        for (int j = 0; j < 4; ++j) acc[i][j] = (f4v){0.f, 0.f, 0.f, 0.f};

    // staging: chunk c = r*512+tid -> row r*64 + (tid>>3), 16B-chunk tid&7
    const int srow = tid >> 3;            // 0..63
    const int sj = tid & 7;
    const int sjx = sj ^ (srow & 7);      // pre-swizzled source chunk (involution)
    const unsigned short* gA = A + (size_t)(m0 + srow) * K + sjx * 8;
    const unsigned short* gB = Bt + (size_t)(n0 + srow) * K + sjx * 8;
    const size_t rstride = (size_t)64 * K;
    unsigned short* lA = &As[0][0] + tid * 8;   // +buf*16384, +r*4096
    unsigned short* lB = &Bs[0][0] + tid * 8;

#define STAGE256(buf, t)                                               \
    {                                                                  \
        const unsigned short* ga_ = gA + (size_t)(t) * 64;             \
        const unsigned short* gb_ = gB + (size_t)(t) * 64;             \
        unsigned short* la_ = lA + (buf) * 16384;                      \
        unsigned short* lb_ = lB + (buf) * 16384;                      \
        _Pragma("unroll")                                              \
        for (int r_ = 0; r_ < 4; ++r_) {                               \
            gload16(ga_ + r_ * rstride, la_ + r_ * 4096);              \
            gload16(gb_ + r_ * rstride, lb_ + r_ * 4096);              \
        }                                                              \
    }

    // read offsets (elts).  row&7 == ln&7 for all fragment rows.
    int aoff[8], boff[4];
#pragma unroll
    for (int mf = 0; mf < 8; ++mf) aoff[mf] = (wm * 128 + mf * 16 + ln) * 64;
#pragma unroll
    for (int nf = 0; nf < 4; ++nf) boff[nf] = (wn * 64 + nf * 16 + ln) * 64;
    const int l7 = ln & 7;
    const int koff0 = ((0 * 4 + q) ^ l7) * 8;   // ks=0
    const int koff1 = ((1 * 4 + q) ^ l7) * 8;   // ks=1

    const int NT = K >> 6;
    STAGE256(0, 0);
    STAGE256(1, 1);
    asm volatile("s_waitcnt vmcnt(8)" ::: "memory");
    __builtin_amdgcn_sched_barrier(0);
    __builtin_amdgcn_s_barrier();

    for (int t = 0; t < NT; ++t) {
        const int cur = t & 1;
        const unsigned short* as = &As[cur][0];
        const unsigned short* bs = &Bs[cur][0];
        bf8v a0[8], b0[4], a1[8], b1[4];
#pragma unroll
        for (int mf = 0; mf < 8; ++mf) a0[mf] = *(const bf8v*)&as[aoff[mf] + koff0];
#pragma unroll
        for (int nf = 0; nf < 4; ++nf) b0[nf] = *(const bf8v*)&bs[boff[nf] + koff0];
#pragma unroll
        for (int mf = 0; mf < 8; ++mf) a1[mf] = *(const bf8v*)&as[aoff[mf] + koff1];
#pragma unroll
        for (int nf = 0; nf < 4; ++nf) b1[nf] = *(const bf8v*)&bs[boff[nf] + koff1];
        __builtin_amdgcn_s_setprio(1);
#pragma unroll
        for (int mf = 0; mf < 8; ++mf)
#pragma unroll
            for (int nf = 0; nf < 4; ++nf)
                acc[mf][nf] = __builtin_amdgcn_mfma_f32_16x16x32_bf16(a0[mf], b0[nf], acc[mf][nf], 0, 0, 0);
        __builtin_amdgcn_s_setprio(0);
        // all ds_reads of buf[cur] complete before anyone overwrites it
        asm volatile("s_waitcnt lgkmcnt(0)" ::: "memory");
        __builtin_amdgcn_sched_barrier(0);
        __builtin_amdgcn_s_barrier();
        if (t + 2 < NT) {
            STAGE256(cur, t + 2);
            asm volatile("s_waitcnt vmcnt(8)" ::: "memory");  // tile t+1 landed
        } else {
            asm volatile("s_waitcnt vmcnt(0)" ::: "memory");
        }
        __builtin_amdgcn_sched_barrier(0);
        __builtin_amdgcn_s_barrier();
        __builtin_amdgcn_s_setprio(1);
#pragma unroll
        for (int mf = 0; mf < 8; ++mf)
#pragma unroll
            for (int nf = 0; nf < 4; ++nf)
                acc[mf][nf] = __builtin_amdgcn_mfma_f32_16x16x32_bf16(a1[mf], b1[nf], acc[mf][nf], 0, 0, 0);
        __builtin_amdgcn_s_setprio(0);
    }
    __builtin_amdgcn_s_barrier();
#undef STAGE256

    // transposed epilogue, per-wave 16x17 tile (intra-wave only)
    float* tb = ((float*)&As[0][0]) + w * 288;
#pragma unroll
    for (int mf = 0; mf < 8; ++mf) {
        const int mbase = m0 + wm * 128 + mf * 16;
        float bi[4];
#pragma unroll
        for (int r = 0; r < 4; ++r) {
            int mm = mbase + q * 4 + r;
            bi[r] = (mm < Mv) ? bias[mm] : 0.f;
        }
#pragma unroll
        for (int nf = 0; nf < 4; ++nf) {
            const int nbase = n0 + wn * 64 + nf * 16;
#pragma unroll
            for (int r = 0; r < 4; ++r) {
                float v = acc[mf][nf][r] + bi[r];
                v = ACT ? tanhf(v) : LRELU(v);
                tb[ln * 17 + q * 4 + r] = v;
            }
#pragma unroll
            for (int r = 0; r < 4; ++r) {
                float v = tb[(q * 4 + r) * 17 + ln];
                int n = nbase + q * 4 + r;
                int m = mbase + ln;
                if (m < Mv) {
                    if (OF32) ((float*)outv)[(size_t)n * ldout + m] = v;
                    else ((unsigned short*)outv)[(size_t)n * ldout + m] = f2b(v);
                }
            }
        }
    }
}

// ---------------------------------------------------------------------------
// K5c: conv3x3-as-GEMM with implicit im2col (2-phase; kept for layer 1).
// ---------------------------------------------------------------------------
template <int TAPK, int CST, int SH, int REMAP>
__global__ __launch_bounds__(256) void k_cgemm(
    const unsigned short* __restrict__ A, const unsigned short* __restrict__ Bt,
    const float* __restrict__ bias, unsigned short* __restrict__ outp,
    int Mv, int ldout) {
    __shared__ __align__(16) unsigned short As[128 * 32];
    __shared__ __align__(16) unsigned short Bs[128 * 32];
    const int tid = threadIdx.x;
    const int lane = tid & 63;
    const int w = tid >> 6;
    const int wm = w >> 1, wn = w & 1;
    const int q = lane >> 4, ln = lane & 15;
    const int m0 = blockIdx.y * 128, n0 = blockIdx.x * 128;
    const int KA = 9 * TAPK;

    f4v acc[4][4];
#pragma unroll
    for (int i = 0; i < 4; ++i)
#pragma unroll
        for (int j = 0; j < 4; ++j) acc[i][j] = (f4v){0.f, 0.f, 0.f, 0.f};

    const int br0 = tid >> 2, bk0 = (tid & 3) << 3;
    const unsigned short* pA0 = A + (size_t)(m0 + br0) * KA + bk0;
    const unsigned short* pA1 = pA0 + (size_t)64 * KA;
    unsigned short* lA0 = As + tid * 8;
    unsigned short* lA1 = As + 2048 + tid * 8;
    unsigned short* lB0 = Bs + tid * 8;
    unsigned short* lB1 = Bs + 2048 + tid * 8;
    const unsigned short* Ap2 = &As[(wm * 64 + ln) * 32 + q * 8];
    const unsigned short* Bp2 = &Bs[(wn * 64 + ln) * 32 + q * 8];

#pragma unroll
    for (int tap = 0; tap < 9; ++tap) {
        const int sh = (tap / 3 - 1) * SH + (tap % 3 - 1);
        const unsigned short* pB0 = Bt + (long)(n0 + br0 + sh) * CST + bk0;
        const unsigned short* pB1 = pB0 + (long)64 * CST;
        const int kab = tap * TAPK;
        for (int kk = 0; kk < TAPK; kk += 32) {
            gload16(pA0 + kab + kk, lA0);
            gload16(pA1 + kab + kk, lA1);
            gload16(pB0 + kk, lB0);
            gload16(pB1 + kk, lB1);
            __syncthreads();
            bf8v af[4], bfv[4];
#pragma unroll
            for (int i = 0; i < 4; ++i) af[i] = *(const bf8v*)(Ap2 + i * 512);
#pragma unroll
            for (int j = 0; j < 4; ++j) bfv[j] = *(const bf8v*)(Bp2 + j * 512);
#pragma unroll
            for (int i = 0; i < 4; ++i)
#pragma unroll
                for (int j = 0; j < 4; ++j)
                    acc[i][j] = __builtin_amdgcn_mfma_f32_16x16x32_bf16(af[i], bfv[j], acc[i][j], 0, 0, 0);
            __syncthreads();
        }
    }

    float* tb = ((float*)As) + w * 288;
#pragma unroll
    for (int i = 0; i < 4; ++i) {
        const int mbase = m0 + wm * 64 + i * 16;
        float bi[4];
#pragma unroll
        for (int r = 0; r < 4; ++r) {
            int mm = mbase + q * 4 + r;
            bi[r] = (mm < Mv) ? bias[mm] : 0.f;
        }
#pragma unroll
        for (int j = 0; j < 4; ++j) {
            const int nbase = n0 + wn * 64 + j * 16;
#pragma unroll
            for (int r = 0; r < 4; ++r) {
                float v = acc[i][j][r] + bi[r];
                v = LRELU(v);
                tb[ln * 17 + q * 4 + r] = v;
            }
#pragma unroll
            for (int r = 0; r < 4; ++r) {
                float v = tb[(q * 4 + r) * 17 + ln];
                int n = nbase + q * 4 + r;
                int m = mbase + ln;
                if (m < Mv) {
                    if (REMAP == 1) {
                        int y = n / 194, x = n - y * 194;
                        bool z = (n >= 37636) || y == 0 || y >= 193 || x == 0 || x >= 193;
                        outp[(size_t)n * ldout + m] = f2b(z ? 0.f : v);
                    } else if (REMAP == 2) {
                        int y = n / 50, x = n - y * 50;
                        bool z = (n >= 2500) || y == 0 || y >= 49 || x == 0 || x >= 49;
                        outp[(size_t)n * ldout + m] = f2b(z ? 0.f : v);
                    } else if (REMAP == 4) {
                        int y = n / 50, x = n - y * 50;
                        if (n < 2500 && y >= 1 && y <= 48 && x >= 1 && x <= 48)
                            outp[(size_t)((y - 1) * 48 + (x - 1)) * ldout + m] = f2b(v);
                    }
                }
            }
        }
    }
}

// ---------------------------------------------------------------------------
// K5cp: PIPELINED conv3x3-as-GEMM (shifted-B implicit im2col) using the
// round-3-verified gemm256 sync skeleton: BK=64, dbuf LDS, stage tile t+2,
// vmcnt(8) (never 0 mid-loop), lgkm0->bar->stage->vmcnt->bar, setprio MFMA
// clusters, same XOR LDS swizzle.  128x128 tile, 4 waves (2M x 2N).
// Tile kt -> tap = kt/TPT, kk = (kt%TPT)*64; k ascending per tap ->
// accumulation order identical to k_cgemm (bit-identical output).
// Requires TAPK % 64 == 0.
// ---------------------------------------------------------------------------
template <int TAPK, int CST, int SH, int REMAP>
__global__ __launch_bounds__(256, 1) void k_cgemm_p(
    const unsigned short* __restrict__ A, const unsigned short* __restrict__ Bt,
    const float* __restrict__ bias, unsigned short* __restrict__ outp,
    int Mv, int ldout) {
    __shared__ __align__(16) unsigned short As[2][8192];   // [128][64] x2
    __shared__ __align__(16) unsigned short Bs[2][8192];
    const int tid = threadIdx.x;          // 0..255
    const int lane = tid & 63;
    const int w = tid >> 6;               // 0..3
    const int wm = w >> 1, wn = w & 1;
    const int q = lane >> 4, ln = lane & 15;
    const int m0 = blockIdx.y * 128, n0 = blockIdx.x * 128;
    const int KA = 9 * TAPK;
    const int TPT = TAPK / 64;            // tiles per tap
    const int NTT = 9 * TPT;

    f4v acc[4][4];
#pragma unroll
    for (int i = 0; i < 4; ++i)
#pragma unroll
        for (int j = 0; j < 4; ++j) acc[i][j] = (f4v){0.f, 0.f, 0.f, 0.f};

    // staging: 256 thr, row srow = tid>>3 (0..31), chunk sj = tid&7 (8 chunks
    // cover a full 64-elem row); 4 issues of 32 rows each -> 128 rows.
    const int srow = tid >> 3;
    const int sj = tid & 7;
    const int sjx = sj ^ (srow & 7);      // pre-swizzled source chunk
    const unsigned short* gAx = A + (size_t)(m0 + srow) * KA + sjx * 8;
    unsigned short* lA = &As[0][0] + tid * 8;
    unsigned short* lB = &Bs[0][0] + tid * 8;

#define STAGEP(buf, t)                                                        \
    {                                                                         \
        int tap_ = (t) / TPT, kk_ = ((t) - tap_ * TPT) * 64;                  \
        int sh_ = (tap_ / 3 - 1) * SH + (tap_ % 3 - 1);                       \
        const unsigned short* ga_ = gAx + tap_ * TAPK + kk_;                  \
        const unsigned short* gb_ =                                           \
            Bt + (long)(n0 + srow + sh_) * CST + kk_ + sjx * 8;               \
        unsigned short* la_ = lA + (buf) * 8192;                              \
        unsigned short* lb_ = lB + (buf) * 8192;                              \
        _Pragma("unroll")                                                     \
        for (int r_ = 0; r_ < 4; ++r_) {                                      \
            gload16(ga_ + (size_t)r_ * 32 * KA, la_ + r_ * 2048);             \
            gload16(gb_ + (long)r_ * 32 * CST, lb_ + r_ * 2048);              \
        }                                                                     \
    }

    // read offsets (elts); fragment row&7 == ln&7 -> same-involution XOR.
    int aoff[4], boff[4];
#pragma unroll
    for (int mf = 0; mf < 4; ++mf) aoff[mf] = (wm * 64 + mf * 16 + ln) * 64;
#pragma unroll
    for (int nf = 0; nf < 4; ++nf) boff[nf] = (wn * 64 + nf * 16 + ln) * 64;
    const int l7 = ln & 7;
    const int koff0 = ((0 * 4 + q) ^ l7) * 8;
    const int koff1 = ((1 * 4 + q) ^ l7) * 8;

    STAGEP(0, 0);
    STAGEP(1, 1);
    asm volatile("s_waitcnt vmcnt(8)" ::: "memory");
    __builtin_amdgcn_sched_barrier(0);
    __builtin_amdgcn_s_barrier();

    for (int t = 0; t < NTT; ++t) {
        const int cur = t & 1;
        const unsigned short* as = &As[cur][0];
        const unsigned short* bs = &Bs[cur][0];
        bf8v a0[4], b0[4], a1[4], b1[4];
#pragma unroll
        for (int mf = 0; mf < 4; ++mf) a0[mf] = *(const bf8v*)&as[aoff[mf] + koff0];
#pragma unroll
        for (int nf = 0; nf < 4; ++nf) b0[nf] = *(const bf8v*)&bs[boff[nf] + koff0];
#pragma unroll
        for (int mf = 0; mf < 4; ++mf) a1[mf] = *(const bf8v*)&as[aoff[mf] + koff1];
#pragma unroll
        for (int nf = 0; nf < 4; ++nf) b1[nf] = *(const bf8v*)&bs[boff[nf] + koff1];
        __builtin_amdgcn_s_setprio(1);
#pragma unroll
        for (int mf = 0; mf < 4; ++mf)
#pragma unroll
            for (int nf = 0; nf < 4; ++nf)
                acc[mf][nf] = __builtin_amdgcn_mfma_f32_16x16x32_bf16(a0[mf], b0[nf], acc[mf][nf], 0, 0, 0);
        __builtin_amdgcn_s_setprio(0);
        asm volatile("s_waitcnt lgkmcnt(0)" ::: "memory");
        __builtin_amdgcn_sched_barrier(0);
        __builtin_amdgcn_s_barrier();
        if (t + 2 < NTT) {
            STAGEP(cur, t + 2);
            asm volatile("s_waitcnt vmcnt(8)" ::: "memory");
        } else {
            asm volatile("s_waitcnt vmcnt(0)" ::: "memory");
        }
        __builtin_amdgcn_sched_barrier(0);
        __builtin_amdgcn_s_barrier();
        __builtin_amdgcn_s_setprio(1);
#pragma unroll
        for (int mf = 0; mf < 4; ++mf)
#pragma unroll
            for (int nf = 0; nf < 4; ++nf)
                acc[mf][nf] = __builtin_amdgcn_mfma_f32_16x16x32_bf16(a1[mf], b1[nf], acc[mf][nf], 0, 0, 0);
        __builtin_amdgcn_s_setprio(0);
    }
    __builtin_amdgcn_s_barrier();
#undef STAGEP

    float* tb = ((float*)&As[0][0]) + w * 288;
#pragma unroll
    for (int i = 0; i < 4; ++i) {
        const int mbase = m0 + wm * 64 + i * 16;
        float bi[4];
#pragma unroll
        for (int r = 0; r < 4; ++r) {
            int mm = mbase + q * 4 + r;
            bi[r] = (mm < Mv) ? bias[mm] : 0.f;
        }
#pragma unroll
        for (int j = 0; j < 4; ++j) {
            const int nbase = n0 + wn * 64 + j * 16;
#pragma unroll
            for (int r = 0; r < 4; ++r) {
                float v = acc[i][j][r] + bi[r];
                v = LRELU(v);
                tb[ln * 17 + q * 4 + r] = v;
            }
#pragma unroll
            for (int r = 0; r < 4; ++r) {
                float v = tb[(q * 4 + r) * 17 + ln];
                int n = nbase + q * 4 + r;
                int m = mbase + ln;
                if (m < Mv) {
                    if (REMAP == 1) {
                        int y = n / 194, x = n - y * 194;
                        bool z = (n >= 37636) || y == 0 || y >= 193 || x == 0 || x >= 193;
                        outp[(size_t)n * ldout + m] = f2b(z ? 0.f : v);
                    } else if (REMAP == 2) {
                        int y = n / 50, x = n - y * 50;
                        bool z = (n >= 2500) || y == 0 || y >= 49 || x == 0 || x >= 49;
                        outp[(size_t)n * ldout + m] = f2b(z ? 0.f : v);
                    } else if (REMAP == 4) {
                        int y = n / 50, x = n - y * 50;
                        if (n < 2500 && y >= 1 && y <= 48 && x >= 1 && x <= 48)
                            outp[(size_t)((y - 1) * 48 + (x - 1)) * ldout + m] = f2b(v);
                    }
                }
            }
        }
    }
}

// ---------------------------------------------------------------------------
// K5b: legacy reg-staged GEMM with in-loop fp32->bf16 A conversion (fallback)
// ---------------------------------------------------------------------------
template <int ACT, int OF32, int AF32>
__global__ __launch_bounds__(256) void k_gemm_f32a(
    const void* __restrict__ Ain, const unsigned short* __restrict__ Bt,
    const float* __restrict__ bias, void* __restrict__ outv,
    int K, int Mv, int ldout) {
    __shared__ __align__(16) unsigned short As[128 * 40];
    __shared__ __align__(16) unsigned short Bs[128 * 40];
    const int tid = threadIdx.x;
    const int lane = tid & 63;
    const int w = tid >> 6;
    const int wm = w >> 1, wn = w & 1;
    const int q = lane >> 4, ln = lane & 15;
    const int m0 = blockIdx.y * 128, n0 = blockIdx.x * 128;

    f4v acc[4][4];
#pragma unroll
    for (int i = 0; i < 4; ++i)
#pragma unroll
        for (int j = 0; j < 4; ++j) acc[i][j] = (f4v){0.f, 0.f, 0.f, 0.f};

    const int br0 = tid >> 2, bk0 = (tid & 3) << 3;
    const int br1 = br0 + 64;
    const int bl0 = br0 * 40 + bk0, bl1 = br1 * 40 + bk0;
    const unsigned short* pB0 = Bt + (size_t)(n0 + br0) * K + bk0;
    const unsigned short* pB1 = Bt + (size_t)(n0 + br1) * K + bk0;

    const unsigned short* Ab = (const unsigned short*)Ain;
    const float* Af = (const float*)Ain;
    const unsigned short* pA0 = Ab + (size_t)(m0 + br0) * K + bk0;
    const unsigned short* pA1 = Ab + (size_t)(m0 + br1) * K + bk0;
    const int fr = tid >> 3, fk = (tid & 7) << 2;
    const float* pF = Af + (size_t)(m0 + fr) * K + fk;

    for (int k0 = 0; k0 < K; k0 += 32) {
        if (AF32) {
#pragma unroll
            for (int jj = 0; jj < 4; ++jj) {
                float4 v = *(const float4*)(pF + (size_t)jj * 32 * K + k0);
                unsigned int lo = ((unsigned)f2b(v.y) << 16) | f2b(v.x);
                unsigned int hi = ((unsigned)f2b(v.w) << 16) | f2b(v.z);
                *(uint2*)&As[(fr + jj * 32) * 40 + fk] = make_uint2(lo, hi);
            }
        } else {
            uint4 a0 = *(const uint4*)(pA0 + k0);
            uint4 a1 = *(const uint4*)(pA1 + k0);
            *(uint4*)&As[bl0] = a0;
            *(uint4*)&As[bl1] = a1;
        }
        uint4 b0 = *(const uint4*)(pB0 + k0);
        uint4 b1 = *(const uint4*)(pB1 + k0);
        *(uint4*)&Bs[bl0] = b0;
        *(uint4*)&Bs[bl1] = b1;
        __syncthreads();
        const unsigned short* Ap2 = &As[(wm * 64 + ln) * 40 + q * 8];
        const unsigned short* Bp2 = &Bs[(wn * 64 + ln) * 40 + q * 8];
        bf8v af[4], bfv[4];
#pragma unroll
        for (int i = 0; i < 4; ++i) af[i] = *(const bf8v*)(Ap2 + i * 640);
#pragma unroll
        for (int j = 0; j < 4; ++j) bfv[j] = *(const bf8v*)(Bp2 + j * 640);
#pragma unroll
        for (int i = 0; i < 4; ++i)
#pragma unroll
            for (int j = 0; j < 4; ++j)
                acc[i][j] = __builtin_amdgcn_mfma_f32_16x16x32_bf16(af[i], bfv[j], acc[i][j], 0, 0, 0);
        __syncthreads();
    }

    float* tb = ((float*)As) + w * 288;
#pragma unroll
    for (int i = 0; i < 4; ++i) {
        const int mbase = m0 + wm * 64 + i * 16;
        float bi[4];
#pragma unroll
        for (int r = 0; r < 4; ++r) {
            int mm = mbase + q * 4 + r;
            bi[r] = (mm < Mv) ? bias[mm] : 0.f;
        }
#pragma unroll
        for (int j = 0; j < 4; ++j) {
            const int nbase = n0 + wn * 64 + j * 16;
#pragma unroll
            for (int r = 0; r < 4; ++r) {
                float v = acc[i][j][r] + bi[r];
                v = ACT ? tanhf(v) : LRELU(v);
                tb[ln * 17 + q * 4 + r] = v;
            }
#pragma unroll
            for (int r = 0; r < 4; ++r) {
                float v = tb[(q * 4 + r) * 17 + ln];
                size_t n = nbase + q * 4 + r;
                int m = mbase + ln;
                if (m < Mv) {
                    if (OF32) ((float*)outv)[n * (size_t)ldout + m] = v;
                    else ((unsigned short*)outv)[n * (size_t)ldout + m] = f2b(v);
                }
            }
        }
    }
}

// ---------------------------------------------------------------------------
// K6: per-pixel normal equations + solve (verified, unchanged)
// ---------------------------------------------------------------------------
__global__ __launch_bounds__(256) void k_solve(const float* __restrict__ WmT,
                                               const float* __restrict__ design,
                                               const float* __restrict__ input,
                                               float* __restrict__ out) {
    const int p = blockIdx.x;  // 0..2303
    const int h = p / 48, wpx = p % 48;
    const int tid = threadIdx.x;
    __shared__ float Msh[16 * 17];
    __shared__ float Gsh[16 * 17];
    __shared__ float Xsh[16 * 8];
    __shared__ float Ysh[16 * 4];
    __shared__ float XTWsh[7 * 17];
    __shared__ float Aacc[49];
    __shared__ float Bacc[21];
    __shared__ float parash[21];

    if (tid < 49) Aacc[tid] = 0.f;
    if (tid >= 64 && tid < 85) Bacc[tid - 64] = 0.f;
    __syncthreads();

    const float* wrow = WmT + (size_t)p * 12544;
    for (int ni = 0; ni < 49; ++ni) {
        {
            int t1 = tid >> 4, t2 = tid & 15;
            Msh[t1 * 17 + t2] = wrow[ni * 256 + tid];
        }
        int sy = h + ni / 7 - 3, sx = wpx + ni % 7 - 3;
        bool inb = (sy >= 0 && sy < 48 && sx >= 0 && sx < 48);
        if (tid < 112) {
            int t = tid / 7, c = tid - t * 7;
            Xsh[t * 8 + c] = inb ? design[(size_t)(t * 7 + c) * 2304 + sy * 48 + sx] : 0.f;
        } else if (tid >= 128 && tid < 176) {
            int l = tid - 128;
            int t = l / 3, r = l - t * 3;
            Ysh[t * 4 + r] = inb ? input[(size_t)(t * 10 + r) * 2304 + sy * 48 + sx] : 0.f;
        }
        __syncthreads();
        {
            int t1 = tid >> 4, t2 = tid & 15;
            float s = (t1 == t2) ? 1.f : 0.f;
#pragma unroll
            for (int k = 0; k < 16; ++k) s += Msh[t1 * 17 + k] * Msh[t2 * 17 + k];
            Gsh[t1 * 17 + t2] = s;
        }
        __syncthreads();
        if (tid < 112) {
            int c = tid >> 4, t2 = tid & 15;
            float s = 0.f;
#pragma unroll
            for (int t1 = 0; t1 < 16; ++t1) s += Xsh[t1 * 8 + c] * Gsh[t1 * 17 + t2];
            XTWsh[c * 17 + t2] = s;
        }
        __syncthreads();
        if (tid < 49) {
            int c1 = tid / 7, c2 = tid - c1 * 7;
            float s = 0.f;
#pragma unroll
            for (int t = 0; t < 16; ++t) s += XTWsh[c1 * 17 + t] * Xsh[t * 8 + c2];
            Aacc[tid] += s;
        } else if (tid >= 64 && tid < 85) {
            int l = tid - 64;
            int c = l / 3, r = l - c * 3;
            float s = 0.f;
#pragma unroll
            for (int t = 0; t < 16; ++t) s += XTWsh[c * 17 + t] * Ysh[t * 4 + r];
            Bacc[l] += s;
        }
        __syncthreads();
    }

    if (tid == 0) {
        float Mg[7][10];
#pragma unroll
        for (int i = 0; i < 7; ++i) {
#pragma unroll
            for (int j = 0; j < 7; ++j) Mg[i][j] = Aacc[i * 7 + j] + ((i == j) ? 0.01f : 0.f);
#pragma unroll
            for (int r = 0; r < 3; ++r) Mg[i][7 + r] = Bacc[i * 3 + r];
        }
#pragma unroll
        for (int kk = 0; kk < 7; ++kk) {
            float inv = 1.f / Mg[kk][kk];
#pragma unroll
            for (int j = 0; j < 10; ++j) Mg[kk][j] *= inv;
#pragma unroll
            for (int i = 0; i < 7; ++i) {
                if (i == kk) continue;
                float f = Mg[i][kk];
#pragma unroll
                for (int j = 0; j < 10; ++j) Mg[i][j] -= f * Mg[kk][j];
            }
        }
#pragma unroll
        for (int c = 0; c < 7; ++c)
#pragma unroll
            for (int r = 0; r < 3; ++r) parash[c * 3 + r] = Mg[c][7 + r];
    }
    __syncthreads();

    if (tid < 48) {
        int t = tid / 3, r = tid - t * 3;
        float s = 0.f;
#pragma unroll
        for (int c = 0; c < 7; ++c)
            s += design[(size_t)(t * 7 + c) * 2304 + p] * parash[c * 3 + r];
        out[(size_t)tid * 2304 + p] = s;
    }
}

// ---------------------------------------------------------------------------
extern "C" void kernel_launch(void* const* d_in, const int* in_sizes, int n_in,
                              void* d_out, int out_size, void* d_ws, size_t ws_size,
                              hipStream_t stream) {
    const float* input   = (const float*)d_in[0];
    const float* design  = (const float*)d_in[1];
    const float* fw0     = (const float*)d_in[2];
    const float* fb0     = (const float*)d_in[3];
    const float* fw_rest = (const float*)d_in[4];
    const float* fb_rest = (const float*)d_in[5];
    const float* ww0     = (const float*)d_in[6];
    const float* wb0     = (const float*)d_in[7];
    const float* ww_mid  = (const float*)d_in[8];
    const float* wb_mid  = (const float*)d_in[9];
    const float* ww1     = (const float*)d_in[10];
    const float* wb1     = (const float*)d_in[11];
    const float* ww2     = (const float*)d_in[12];
    const float* wb2     = (const float*)d_in[13];
    float* out = (float*)d_out;
    float* ws = (float*)d_ws;

    // ---- workspace layout (float units).  Region [0, 28,901,376) is scratch
    // during the conv phase and becomes WmT (fp32 [2304][12544]) at ww2 time.
    float* WmT = ws;
    unsigned short* full0p = (unsigned short*)(ws + 40000);      // [37956][16] sh
    unsigned short* actPA  = (unsigned short*)(ws + 350000);     // [37956][104] sh
    unsigned short* actPB  = (unsigned short*)(ws + 2330000);    // [37956][104] sh
    unsigned short* fw0c   = (unsigned short*)(ws + 4310000);    // [128][288] sh
    unsigned short* fwrb   = (unsigned short*)(ws + 4330000);    // 13 x [128][1152] sh
    unsigned short* ww0b   = (unsigned short*)(ws + 5290000);    // [1024][1600] sh
    unsigned short* col4   = (unsigned short*)(ws + 6110000);    // [2304][1600] sh
    unsigned short* gPA    = (unsigned short*)(ws + 7960000);    // [2688][1024] sh
    unsigned short* gPB    = (unsigned short*)(ws + 9340000);    // [2688][1024] sh
    unsigned short* wmb    = (unsigned short*)(ws + 10720000);   // [1024][9216] sh
    unsigned short* gcmp   = (unsigned short*)(ws + 15440000);   // [2304][1024] sh
    unsigned short* g1     = (unsigned short*)(ws + 28901376);   // [2304][6272] sh
    unsigned short* ww1b   = (unsigned short*)(ws + 36126720);   // fallback slot
    const size_t WS_BASE_F = 39337984ull;
    unsigned short* ww2b   = (unsigned short*)(ws + WS_BASE_F);  // [12544][6272] sh (19,668,992 f)
    unsigned short* ww1bp  = (unsigned short*)(ws + 59006976);   // [6400][1024] sh (3,276,800 f)
    const size_t NEED_BIG = 59006976ull + 3276800ull;            // 62,283,776 f

    // ---- zero padded buffers (ring + tails)
    hipMemsetAsync(full0p, 0, (size_t)37956 * 16 * 2, stream);
    hipMemsetAsync(actPA, 0, (size_t)37956 * 104 * 2, stream);
    hipMemsetAsync(actPB, 0, (size_t)37956 * 104 * 2, stream);
    hipMemsetAsync(gPA, 0, (size_t)2688 * 1024 * 2, stream);
    hipMemsetAsync(gPB, 0, (size_t)2688 * 1024 * 2, stream);

    const size_t haveF = ws_size / 4;
    const bool big = (haveF >= NEED_BIG) && (haveF >= WS_BASE_F + 39337984ull);

    // ---- weight conversions
    k_wcvt<10, 32, 9><<<128, 256, 0, stream>>>(fw0, fw0c, 100, 288);
    for (int i = 0; i < 13; ++i)
        k_wcvt<100, 128, 9><<<128, 256, 0, stream>>>(fw_rest + (size_t)i * 90000,
                                                     fwrb + (size_t)i * 147456, 100, 1152);
    k_wcvt<100, 100, 16><<<1024, 256, 0, stream>>>(ww0, ww0b, 1024, 1600);
    if (big)
        k_wcvt<1024, 1024, 1><<<6400, 256, 0, stream>>>(ww1, ww1bp, 6272, 1024);
    else
        k_wcvt<1024, 1024, 1><<<6272, 256, 0, stream>>>(ww1, ww1b, 6272, 1024);

    // ---- feature network: layer 1 (K/tap=32) on 2-phase cgemm, rest on the
    // pipelined cgemm_p (padded 194x194, shifted-B implicit im2col)
    k_build_full<<<1440, 256, 0, stream>>>(input, full0p);
    k_cgemm<32, 16, 194, 1><<<dim3(295, 1), 256, 0, stream>>>(fw0c, full0p, fb0, actPA, 100, 104);
    unsigned short* src = actPA;
    unsigned short* dst = actPB;
    for (int i = 0; i < 13; ++i) {
        k_cgemm_p<128, 104, 194, 1><<<dim3(295, 1), 256, 0, stream>>>(
            fwrb + (size_t)i * 147456, src, fb_rest + i * 100, dst, 100, 104);
        unsigned short* t = src; src = dst; dst = t;
    }
    // src == final feature map (padded)

    // ---- weight network head: conv4x4 s4 -> padded 50x50 [1024]
    k_im2col4<<<2304, 256, 0, stream>>>(src, col4);
    k_gemm<0, 0, 3, 0><<<dim3(18, 8), 256, 0, stream>>>(ww0b, col4, wb0, gPA, 1600, 1024, 1024);

    // ---- 3 x conv3x3 1024->1024 at 48x48 via pipelined cgemm_p (50x50 pad)
    k_wcvt<1024, 1024, 9><<<1024, 256, 0, stream>>>(ww_mid, wmb, 1024, 9216);
    k_cgemm_p<1024, 1024, 50, 2><<<dim3(20, 8), 256, 0, stream>>>(wmb, gPA, wb_mid, gPB, 1024, 1024);
    k_wcvt<1024, 1024, 9><<<1024, 256, 0, stream>>>(ww_mid + (size_t)9437184, wmb, 1024, 9216);
    k_cgemm_p<1024, 1024, 50, 2><<<dim3(20, 8), 256, 0, stream>>>(wmb, gPB, wb_mid + 1024, gPA, 1024, 1024);
    k_wcvt<1024, 1024, 9><<<1024, 256, 0, stream>>>(ww_mid + (size_t)2 * 9437184, wmb, 1024, 9216);
    k_cgemm_p<1024, 1024, 50, 4><<<dim3(20, 8), 256, 0, stream>>>(wmb, gPA, wb_mid + 2048, gcmp, 1024, 1024);

    // ---- two 1x1 convs (GEMMs)
    if (big) {
        k_gemm256<0, 0, 1><<<dim3(9, 25), 512, 0, stream>>>(ww1bp, gcmp, wb1, g1, 1024, 6272, 6272);
        k_cvt_flat<<<76832, 256, 0, stream>>>(ww2, ww2b, (size_t)12544 * 6272);
        k_gemm256<1, 1, 1><<<dim3(9, 49), 512, 0, stream>>>(ww2b, g1, wb2, WmT, 6272, 12544, 12544);
    } else {
        k_gemm<0, 0, 0, 1><<<dim3(18, 49), 256, 0, stream>>>(ww1b, gcmp, wb1, g1, 1024, 6272, 6272);
        k_gemm_f32a<1, 1, 1><<<dim3(18, 98), 256, 0, stream>>>(ww2, g1, wb2, WmT, 6272, 12544, 12544);
    }

    // ---- per-pixel solve
    k_solve<<<2304, 256, 0, stream>>>(WmT, design, input, out);
}